// Round 9
// baseline (156.855 us; speedup 1.0000x reference)
//
#include <hip/hip_runtime.h>
#include <stdint.h>

// ClusterHead: P = softmax_k( x . c_k - 0.5*||c_k||^2 )   (||x||^2 cancels)
// R9: occupancy fix. All R3-R8 variants sat at 2 waves/SIMD (acc=128 VGPR)
// with every pipe <=22% -- latency-bound, resources serialized. Now:
// 16 waves x (64 rows x 64 cols) tiles -> acc[2][2]=64 VGPR -> <=128 total
// -> 4 waves/SIMD (16 waves/CU, 2x TLP). Wave w handles col-half jh=w>>3,
// col-block wc8=w&7; per slice: its c_hi sub-image then its c_lo sub-image.
// fp16 2-term split: logits ~= x_h.(c_h + c_l); 32x32x16 f16 MFMA.
// B global->VGPR (single buffer, TLP hides latency), A in LDS ping-pong,
// 1 barrier/slice, NT hints on x loads + out stores (kept from R8).

namespace {
constexpr int N_ROWS  = 32768;
constexpr int K_CL    = 1024;
constexpr int D_DIM   = 512;
constexpr int BM      = 64;
constexpr int THREADS = 1024;
constexpr int WAVES   = 16;
constexpr int NSLICE  = 16;     // k-slices of 32
}

typedef _Float16 f16_t;
typedef _Float16 f16x8 __attribute__((ext_vector_type(8)));
typedef _Float16 f16x2 __attribute__((ext_vector_type(2)));
typedef float    f32x16 __attribute__((ext_vector_type(16)));
typedef float    f32x2v __attribute__((ext_vector_type(2)));

// ---- prep: fp16 hi/lo B-pack + bias = -0.5*||c||^2 (fp32 exact)
// sub-image s: s=4t+jh -> c_hi, k-slice t, col-half jh; s=4t+2+jh -> c_lo.
// within: [ks(2)][cb(16)][(c32*2+kh)*8] halfwords (1KB per (ks,cb) block).
__global__ __launch_bounds__(64) void prep_kernel(const float* __restrict__ centers,
                                                  f16_t* __restrict__ bpack,
                                                  float* __restrict__ bias) {
  const int col = blockIdx.x, lane = threadIdx.x;
  const int t  = lane >> 2;          // k-slice of this lane's 8 d's
  const int ks = (lane >> 1) & 1;    // 16-k group
  const int kh = lane & 1;           // 8-k half
  const float* src = centers + (size_t)col * D_DIM + lane * 8;
  f16x8 hi, lo;
  float ssq = 0.f;
  #pragma unroll
  for (int i = 0; i < 8; ++i) {
    float v = src[i];
    ssq += v * v;
    f16_t h = (f16_t)v;
    hi[i] = h;
    lo[i] = (f16_t)(v - (float)h);
  }
  const int jh = col >> 9, cb = (col & 511) >> 5, c32 = col & 31;
  const size_t off = ((size_t)ks * 16 + cb) * 512 + (c32 * 2 + kh) * 8;  // halfwords
  *(f16x8*)(bpack + (size_t)(4 * t + jh)     * 16384 + off) = hi;
  *(f16x8*)(bpack + (size_t)(4 * t + 2 + jh) * 16384 + off) = lo;
  for (int o = 32; o; o >>= 1) ssq += __shfl_down(ssq, o, 64);
  if (lane == 0) bias[col] = -0.5f * ssq;
}

// ---- main fused kernel: 64 rows x 1024 cols per block, 16 waves ----
__global__ __launch_bounds__(THREADS, 1) void cluster_kernel(
    const float* __restrict__ x, const f16_t* __restrict__ bpack,
    const float* __restrict__ bias, float* __restrict__ out) {
  __shared__ f16_t Abuf[2][4][64][8];   // [slice parity][k2][row][e]  8KB
  __shared__ float red[WAVES * BM];     // 4KB
  __shared__ float fin[BM];

  const int tid  = threadIdx.x;
  const int wid  = tid >> 6;            // 0..15
  const int lane = tid & 63;
  const int l31  = lane & 31;
  const int h    = lane >> 5;
  const int jh   = wid >> 3;            // col half (0..1)
  const int wc8  = wid & 7;             // 64-col block within half
  const int brow = blockIdx.x * BM;
  const int xrow = tid >> 4, q16 = tid & 15;   // CONVERT mapping (1024 thr)

  f32x16 acc[2][2];
  #pragma unroll
  for (int rb = 0; rb < 2; ++rb)
    #pragma unroll
    for (int c2 = 0; c2 < 2; ++c2)
      #pragma unroll
      for (int e = 0; e < 16; ++e) acc[rb][c2][e] = 0.f;

  // per-lane base into a sub-image: wave's 2KB (2 cb-blocks) at wc8*2048
  const char* bbase = (const char*)bpack + wc8 * 2048 + (l31 * 2 + h) * 16;
  const float* xbase = x + (size_t)(brow + xrow) * D_DIM + q16 * 2;

#define LOADB(S)                                                               \
  {                                                                            \
    const char* p_ = bbase + (size_t)(S) * 32768;                              \
    b[0] = *(const f16x8*)(p_);            /* ks0, c2=0 */                     \
    b[1] = *(const f16x8*)(p_ + 1024);     /* ks0, c2=1 */                     \
    b[2] = *(const f16x8*)(p_ + 16384);    /* ks1, c2=0 */                     \
    b[3] = *(const f16x8*)(p_ + 17408);    /* ks1, c2=1 */                     \
  }
#define CONVERT(XV, PAR)                                                       \
  {                                                                            \
    const int kk_ = q16 * 2;                                                   \
    f16x2 h2_;                                                                 \
    h2_[0] = (f16_t)(XV)[0];                                                   \
    h2_[1] = (f16_t)(XV)[1];                                                   \
    *(f16x2*)&Abuf[(PAR)][kk_ >> 3][xrow][kk_ & 7] = h2_;                      \
  }
#define COMPUTE()                                                              \
  {                                                                            \
    _Pragma("unroll")                                                          \
    for (int ks_ = 0; ks_ < 2; ++ks_)                                          \
      _Pragma("unroll")                                                        \
      for (int c2_ = 0; c2_ < 2; ++c2_)                                        \
        _Pragma("unroll")                                                      \
        for (int rb_ = 0; rb_ < 2; ++rb_)                                      \
          acc[rb_][c2_] = __builtin_amdgcn_mfma_f32_32x32x16_f16(              \
              a[rb_][ks_], b[ks_ * 2 + c2_], acc[rb_][c2_], 0, 0, 0);          \
  }

  f16x8 b[4];
  f16x8 a[2][2];

  // ---- prologue: convert x slice 0 ----
  {
    f32x2v xv0 = __builtin_nontemporal_load((const f32x2v*)xbase);
    CONVERT(xv0, 0)
  }
  __syncthreads();

  // ---- main loop: 16 slices x 2 sub-images (this wave's jh half) ----
  #pragma unroll 1
  for (int t = 0; t < NSLICE; ++t) {
    // A-fragments for this slice (written during slice t-1, fenced by barrier)
    #pragma unroll
    for (int rb = 0; rb < 2; ++rb)
      #pragma unroll
      for (int ks = 0; ks < 2; ++ks)
        a[rb][ks] = *(const f16x8*)&Abuf[t & 1][ks * 2 + h][rb * 32 + l31][0];

    // x for next slice (NT, consumed at CONVERT below)
    f32x2v xv = __builtin_nontemporal_load(
        (const f32x2v*)(xbase + ((t + 1) & 15) * 32));

    // c_hi sub-image of this wave's half
    LOADB(4 * t + jh)
    COMPUTE()

    // c_lo sub-image
    LOADB(4 * t + 2 + jh)
    COMPUTE()

    CONVERT(xv, (t + 1) & 1)
    __syncthreads();   // A(t+1) visible to all waves
  }

  // ---- epilogue: fused softmax over 1024 columns ----
  // col(c2) = jh*512 + wc8*64 + c2*32 + l31
  // row(rb,reg) = rb*32 + (reg&3) + 8*(reg>>2) + 4*h
  float bcol[2];
  #pragma unroll
  for (int c2 = 0; c2 < 2; ++c2)
    bcol[c2] = bias[jh * 512 + wc8 * 64 + c2 * 32 + l31];

  float rr[2][16];
  #pragma unroll
  for (int rb = 0; rb < 2; ++rb)
    #pragma unroll
    for (int reg = 0; reg < 16; ++reg) {
      float v0 = acc[rb][0][reg] + bcol[0];
      float v1 = acc[rb][1][reg] + bcol[1];
      acc[rb][0][reg] = v0;
      acc[rb][1][reg] = v1;
      float m = fmaxf(v0, v1);
      m = fmaxf(m, __shfl_xor(m, 1, 64));
      m = fmaxf(m, __shfl_xor(m, 2, 64));
      m = fmaxf(m, __shfl_xor(m, 4, 64));
      m = fmaxf(m, __shfl_xor(m, 8, 64));
      m = fmaxf(m, __shfl_xor(m, 16, 64));
      rr[rb][reg] = m;
    }
  if (l31 == 0) {   // lanes 0 and 32 (h=0,1) write their distinct rows
    #pragma unroll
    for (int rb = 0; rb < 2; ++rb)
      #pragma unroll
      for (int reg = 0; reg < 16; ++reg)
        red[wid * BM + rb * 32 + (reg & 3) + 8 * (reg >> 2) + 4 * h] = rr[rb][reg];
  }
  __syncthreads();
  if (tid < BM) {
    float m = red[tid];
    #pragma unroll
    for (int w = 1; w < WAVES; ++w) m = fmaxf(m, red[w * BM + tid]);
    fin[tid] = m;
  }
  __syncthreads();

  #pragma unroll
  for (int rb = 0; rb < 2; ++rb)
    #pragma unroll
    for (int reg = 0; reg < 16; ++reg) {
      const float m = fin[rb * 32 + (reg & 3) + 8 * (reg >> 2) + 4 * h];
      float e0 = __expf(acc[rb][0][reg] - m);
      float e1 = __expf(acc[rb][1][reg] - m);
      acc[rb][0][reg] = e0;
      acc[rb][1][reg] = e1;
      float s = e0 + e1;
      s += __shfl_xor(s, 1, 64);
      s += __shfl_xor(s, 2, 64);
      s += __shfl_xor(s, 4, 64);
      s += __shfl_xor(s, 8, 64);
      s += __shfl_xor(s, 16, 64);
      rr[rb][reg] = s;
    }
  __syncthreads();   // fin(max) reads done before red overwrite
  if (l31 == 0) {
    #pragma unroll
    for (int rb = 0; rb < 2; ++rb)
      #pragma unroll
      for (int reg = 0; reg < 16; ++reg)
        red[wid * BM + rb * 32 + (reg & 3) + 8 * (reg >> 2) + 4 * h] = rr[rb][reg];
  }
  __syncthreads();
  if (tid < BM) {
    float s = 0.f;
    #pragma unroll
    for (int w = 0; w < WAVES; ++w) s += red[w * BM + tid];
    fin[tid] = 1.0f / s;
  }
  __syncthreads();

  #pragma unroll
  for (int rb = 0; rb < 2; ++rb)
    #pragma unroll
    for (int reg = 0; reg < 16; ++reg) {
      const int row = rb * 32 + (reg & 3) + 8 * (reg >> 2) + 4 * h;
      const float rs = fin[row];
      #pragma unroll
      for (int c2 = 0; c2 < 2; ++c2) {
        const int col = jh * 512 + wc8 * 64 + c2 * 32 + l31;
        __builtin_nontemporal_store(acc[rb][c2][reg] * rs,
                                    &out[(size_t)(brow + row) * K_CL + col]);
      }
    }
}

extern "C" void kernel_launch(void* const* d_in, const int* in_sizes, int n_in,
                              void* d_out, int out_size, void* d_ws, size_t ws_size,
                              hipStream_t stream) {
  const float* x       = (const float*)d_in[0];   // [32768, 512] fp32
  const float* centers = (const float*)d_in[1];   // [1024, 512] fp32
  float* out = (float*)d_out;                     // [32768, 1024] fp32

  f16_t* bpack = (f16_t*)d_ws;                                   // 64*32KB = 2MB
  float* bias  = (float*)((char*)d_ws + (size_t)64 * 32768);     // 4KB

  prep_kernel<<<K_CL, 64, 0, stream>>>(centers, bpack, bias);
  cluster_kernel<<<N_ROWS / BM, THREADS, 0, stream>>>(x, bpack, bias, out);
}

// Round 10
// 95.541 us; speedup vs baseline: 1.6417x; 1.6417x over previous
//
#include <hip/hip_runtime.h>
#include <stdint.h>

// ClusterHead: P = softmax_k( x . c_k - 0.5*||c_k||^2 )   (||x||^2 cancels)
// R10: SINGLE-term fp16 GEMM: logits ~= fp16(x) . fp16(c). fp16's 11-bit
// mantissa makes the c_lo refinement term unnecessary (measured: dropping
// x_lo cost +0.0039 absmax; c_lo is symmetric -> predicted ~0.012 < 0.02).
// Halves B L2-traffic (the measured binding term) AND MFMA work vs R8.
// Structure = R8 (best measured): 8 waves, B global->VGPR reg double-buffer
// distance-1, A in LDS ping-pong, 1 barrier/slice, NT hints on x/out,
// x prefetch distance-2 (NT ~900cy > shortened slice body).
// B-pack: 32 sub-images of 32KB; s = 2t + jh (k-slice t, col-half jh);
// within: [ks(2)][cb(16)][(c32*2+kh)*8] halfwords (1KB per (ks,cb) block).
// MFMA 32x32x16 f16; C/D: col=l31, row=(reg&3)+8*(reg>>2)+4*(lane>>5).

namespace {
constexpr int N_ROWS  = 32768;
constexpr int K_CL    = 1024;
constexpr int D_DIM   = 512;
constexpr int BM      = 64;
constexpr int THREADS = 512;
constexpr int WAVES   = 8;
constexpr int NSLICE  = 16;     // k-slices of 32
}

typedef _Float16 f16_t;
typedef _Float16 f16x8 __attribute__((ext_vector_type(8)));
typedef _Float16 f16x4 __attribute__((ext_vector_type(4)));
typedef float    f32x16 __attribute__((ext_vector_type(16)));
typedef float    f32x4v __attribute__((ext_vector_type(4)));

// ---- prep: fp16 B-pack + bias = -0.5*||c||^2 (fp32 exact)
__global__ __launch_bounds__(64) void prep_kernel(const float* __restrict__ centers,
                                                  f16_t* __restrict__ bpack,
                                                  float* __restrict__ bias) {
  const int col = blockIdx.x, lane = threadIdx.x;
  const int t  = lane >> 2;          // k-slice of this lane's 8 d's
  const int ks = (lane >> 1) & 1;    // 16-k group
  const int kh = lane & 1;           // 8-k half
  const float* src = centers + (size_t)col * D_DIM + lane * 8;
  f16x8 hi;
  float ssq = 0.f;
  #pragma unroll
  for (int i = 0; i < 8; ++i) {
    float v = src[i];
    ssq += v * v;
    hi[i] = (f16_t)v;
  }
  const int jh = col >> 9, cb = (col & 511) >> 5, c32 = col & 31;
  const size_t off = ((size_t)ks * 16 + cb) * 512 + (c32 * 2 + kh) * 8;  // halfwords
  *(f16x8*)(bpack + (size_t)(2 * t + jh) * 16384 + off) = hi;
  for (int o = 32; o; o >>= 1) ssq += __shfl_down(ssq, o, 64);
  if (lane == 0) bias[col] = -0.5f * ssq;
}

// ---- main fused kernel: 64 rows x 1024 cols per block ----
__global__ __launch_bounds__(THREADS, 2) void cluster_kernel(
    const float* __restrict__ x, const f16_t* __restrict__ bpack,
    const float* __restrict__ bias, float* __restrict__ out) {
  __shared__ f16_t Abuf[2][4][64][8];   // [slice parity][k2][row][e]  8KB
  __shared__ float red[WAVES * BM];     // 2KB
  __shared__ float fin[BM];

  const int tid  = threadIdx.x;
  const int wid  = tid >> 6;
  const int lane = tid & 63;
  const int l31  = lane & 31;
  const int h    = lane >> 5;
  const int brow = blockIdx.x * BM;
  const int xrow = tid >> 3, q8 = tid & 7;

  f32x16 acc[2][4];
  #pragma unroll
  for (int rb = 0; rb < 2; ++rb)
    #pragma unroll
    for (int cc = 0; cc < 4; ++cc)
      #pragma unroll
      for (int e = 0; e < 16; ++e) acc[rb][cc][e] = 0.f;

  // per-lane byte base into a sub-image (wave's 2 cb-blocks start at wid*2048)
  const char* bbase = (const char*)bpack + wid * 2048 + (l31 * 2 + h) * 16;
  const float* xbase = x + (size_t)(brow + xrow) * D_DIM + q8 * 4;

#define LOADB(S, DST)                                                          \
  {                                                                            \
    const char* p_ = bbase + (size_t)((S) & 31) * 32768;                       \
    (DST)[0] = *(const f16x8*)(p_);            /* ks0, cb even */              \
    (DST)[1] = *(const f16x8*)(p_ + 1024);     /* ks0, cb odd  */              \
    (DST)[2] = *(const f16x8*)(p_ + 16384);    /* ks1, cb even */              \
    (DST)[3] = *(const f16x8*)(p_ + 17408);    /* ks1, cb odd  */              \
  }
#define CONVERT(XV, PAR)                                                       \
  {                                                                            \
    f16x4 h4_;                                                                 \
    h4_[0] = (f16_t)(XV)[0]; h4_[1] = (f16_t)(XV)[1];                          \
    h4_[2] = (f16_t)(XV)[2]; h4_[3] = (f16_t)(XV)[3];                          \
    *(f16x4*)&Abuf[(PAR)][q8 >> 1][xrow][(q8 & 1) * 4] = h4_;                  \
  }
#define COMPUTE(B, JH)                                                         \
  {                                                                            \
    _Pragma("unroll")                                                          \
    for (int ks_ = 0; ks_ < 2; ++ks_)                                          \
      _Pragma("unroll")                                                        \
      for (int c2_ = 0; c2_ < 2; ++c2_) {                                      \
        _Pragma("unroll")                                                      \
        for (int rb_ = 0; rb_ < 2; ++rb_)                                      \
          acc[rb_][(JH) * 2 + c2_] = __builtin_amdgcn_mfma_f32_32x32x16_f16(   \
              a[rb_][ks_], (B)[ks_ * 2 + c2_], acc[rb_][(JH) * 2 + c2_],       \
              0, 0, 0);                                                        \
      }                                                                        \
  }

  f16x8 bcur[4], bnxt[4];
  f16x8 a[2][2];

  // ---- prologue: convert x(0); prefetch B(0); issue x(1) ----
  {
    f32x4v xv0 = __builtin_nontemporal_load((const f32x4v*)xbase);
    CONVERT(xv0, 0)
  }
  LOADB(0, bcur)
  f32x4v xc = __builtin_nontemporal_load((const f32x4v*)(xbase + 32));
  __syncthreads();

  // ---- main loop: 16 slices x 2 sub-images ----
  #pragma unroll 1
  for (int t = 0; t < NSLICE; ++t) {
    #pragma unroll
    for (int rb = 0; rb < 2; ++rb)
      #pragma unroll
      for (int ks = 0; ks < 2; ++ks)
        a[rb][ks] = *(const f16x8*)&Abuf[t & 1][ks * 2 + h][rb * 32 + l31][0];

    // J0: col-half 0
    LOADB(2 * t + 1, bnxt)
    f32x4v xn = __builtin_nontemporal_load(
        (const f32x4v*)(xbase + ((t + 2) & 15) * 32));
    COMPUTE(bcur, 0)

    // J1: col-half 1; prefetch next slice's half0 (wrapped at tail)
    LOADB(2 * t + 2, bcur)
    COMPUTE(bnxt, 1)

    CONVERT(xc, (t + 1) & 1)
    __syncthreads();   // A(t+1) visible; bounds wave skew
    xc = xn;
  }

  // ---- epilogue: fused softmax over 1024 columns ----
  // col(cc) = (cc>>1)*512 + wid*64 + (cc&1)*32 + l31
  // row(rb,reg) = rb*32 + (reg&3) + 8*(reg>>2) + 4*h
  float bcol[4];
  #pragma unroll
  for (int cc = 0; cc < 4; ++cc)
    bcol[cc] = bias[(cc >> 1) * 512 + wid * 64 + (cc & 1) * 32 + l31];

  float rr[2][16];
  #pragma unroll
  for (int rb = 0; rb < 2; ++rb)
    #pragma unroll
    for (int reg = 0; reg < 16; ++reg) {
      float m = -3.0e38f;
      #pragma unroll
      for (int cc = 0; cc < 4; ++cc) {
        float v = acc[rb][cc][reg] + bcol[cc];
        acc[rb][cc][reg] = v;
        m = fmaxf(m, v);
      }
      m = fmaxf(m, __shfl_xor(m, 1, 64));
      m = fmaxf(m, __shfl_xor(m, 2, 64));
      m = fmaxf(m, __shfl_xor(m, 4, 64));
      m = fmaxf(m, __shfl_xor(m, 8, 64));
      m = fmaxf(m, __shfl_xor(m, 16, 64));
      rr[rb][reg] = m;
    }
  if (l31 == 0) {   // lanes 0 and 32 (h=0,1) cover distinct rows
    #pragma unroll
    for (int rb = 0; rb < 2; ++rb)
      #pragma unroll
      for (int reg = 0; reg < 16; ++reg)
        red[wid * BM + rb * 32 + (reg & 3) + 8 * (reg >> 2) + 4 * h] = rr[rb][reg];
  }
  __syncthreads();
  if (tid < BM) {
    float m = red[tid];
    #pragma unroll
    for (int w = 1; w < WAVES; ++w) m = fmaxf(m, red[w * BM + tid]);
    fin[tid] = m;
  }
  __syncthreads();

  #pragma unroll
  for (int rb = 0; rb < 2; ++rb)
    #pragma unroll
    for (int reg = 0; reg < 16; ++reg) {
      const float m = fin[rb * 32 + (reg & 3) + 8 * (reg >> 2) + 4 * h];
      float s = 0.f;
      #pragma unroll
      for (int cc = 0; cc < 4; ++cc) {
        float e = __expf(acc[rb][cc][reg] - m);
        acc[rb][cc][reg] = e;
        s += e;
      }
      s += __shfl_xor(s, 1, 64);
      s += __shfl_xor(s, 2, 64);
      s += __shfl_xor(s, 4, 64);
      s += __shfl_xor(s, 8, 64);
      s += __shfl_xor(s, 16, 64);
      rr[rb][reg] = s;
    }
  __syncthreads();   // fin(max) reads done before red overwrite
  if (l31 == 0) {
    #pragma unroll
    for (int rb = 0; rb < 2; ++rb)
      #pragma unroll
      for (int reg = 0; reg < 16; ++reg)
        red[wid * BM + rb * 32 + (reg & 3) + 8 * (reg >> 2) + 4 * h] = rr[rb][reg];
  }
  __syncthreads();
  if (tid < BM) {
    float s = 0.f;
    #pragma unroll
    for (int w = 0; w < WAVES; ++w) s += red[w * BM + tid];
    fin[tid] = 1.0f / s;
  }
  __syncthreads();

  #pragma unroll
  for (int rb = 0; rb < 2; ++rb)
    #pragma unroll
    for (int reg = 0; reg < 16; ++reg) {
      const int row = rb * 32 + (reg & 3) + 8 * (reg >> 2) + 4 * h;
      const float rs = fin[row];
      #pragma unroll
      for (int cc = 0; cc < 4; ++cc) {
        const int col = (cc >> 1) * 512 + wid * 64 + (cc & 1) * 32 + l31;
        __builtin_nontemporal_store(acc[rb][cc][reg] * rs,
                                    &out[(size_t)(brow + row) * K_CL + col]);
      }
    }
}

extern "C" void kernel_launch(void* const* d_in, const int* in_sizes, int n_in,
                              void* d_out, int out_size, void* d_ws, size_t ws_size,
                              hipStream_t stream) {
  const float* x       = (const float*)d_in[0];   // [32768, 512] fp32
  const float* centers = (const float*)d_in[1];   // [1024, 512] fp32
  float* out = (float*)d_out;                     // [32768, 1024] fp32

  f16_t* bpack = (f16_t*)d_ws;                                   // 32*32KB = 1MB
  float* bias  = (float*)((char*)d_ws + (size_t)32 * 32768);     // 4KB

  prep_kernel<<<K_CL, 64, 0, stream>>>(centers, bpack, bias);
  cluster_kernel<<<N_ROWS / BM, THREADS, 0, stream>>>(x, bpack, bias, out);
}

// Round 11
// 89.234 us; speedup vs baseline: 1.7578x; 1.0707x over previous
//
#include <hip/hip_runtime.h>
#include <stdint.h>

// ClusterHead: P = softmax_k( x . c_k - 0.5*||c_k||^2 )   (||x||^2 cancels)
// R11: BARRIER-FREE main loop. Whole 64x512 fp16 A-panel staged to LDS once
// (XOR-swizzled), then 16 k-slices of pure dataflow: 4 ds_read + 8 global
// B loads (full-slice prefetch distance) + 16 MFMA per wave, no syncs.
// Single-term fp16 GEMM (R10-validated: absmax 0.0078), 32x32x16 f16 MFMA,
// NT hints on x loads / out stores.
// B-pack: 32 sub-images of 32KB; s = 2t + jh; within: [ks(2)][cb(16)]
// [(c32*2+kh)*8] halfwords. A LDS: row-major [64][512] f16, byte offset
// row*1024 + (k*2 ^ ((row&7)<<4)).

namespace {
constexpr int N_ROWS  = 32768;
constexpr int K_CL    = 1024;
constexpr int D_DIM   = 512;
constexpr int BM      = 64;
constexpr int THREADS = 512;
constexpr int WAVES   = 8;
constexpr int NSLICE  = 16;     // k-slices of 32
}

typedef _Float16 f16_t;
typedef _Float16 f16x8 __attribute__((ext_vector_type(8)));
typedef _Float16 f16x4 __attribute__((ext_vector_type(4)));
typedef float    f32x16 __attribute__((ext_vector_type(16)));
typedef float    f32x4v __attribute__((ext_vector_type(4)));

// ---- prep: fp16 B-pack + bias = -0.5*||c||^2 (fp32 exact) ----
__global__ __launch_bounds__(64) void prep_kernel(const float* __restrict__ centers,
                                                  f16_t* __restrict__ bpack,
                                                  float* __restrict__ bias) {
  const int col = blockIdx.x, lane = threadIdx.x;
  const int t  = lane >> 2;          // k-slice of this lane's 8 d's
  const int ks = (lane >> 1) & 1;    // 16-k group
  const int kh = lane & 1;           // 8-k half
  const float* src = centers + (size_t)col * D_DIM + lane * 8;
  f16x8 hi;
  float ssq = 0.f;
  #pragma unroll
  for (int i = 0; i < 8; ++i) {
    float v = src[i];
    ssq += v * v;
    hi[i] = (f16_t)v;
  }
  const int jh = col >> 9, cb = (col & 511) >> 5, c32 = col & 31;
  const size_t off = ((size_t)ks * 16 + cb) * 512 + (c32 * 2 + kh) * 8;  // halfwords
  *(f16x8*)(bpack + (size_t)(2 * t + jh) * 16384 + off) = hi;
  for (int o = 32; o; o >>= 1) ssq += __shfl_down(ssq, o, 64);
  if (lane == 0) bias[col] = -0.5f * ssq;
}

// ---- main fused kernel: 64 rows x 1024 cols per block ----
__global__ __launch_bounds__(THREADS, 2) void cluster_kernel(
    const float* __restrict__ x, const f16_t* __restrict__ bpack,
    const float* __restrict__ bias, float* __restrict__ out) {
  __shared__ __align__(16) char Ax[64 * 1024];   // 64KB swizzled A panel
  __shared__ float red[WAVES * BM];              // 2KB
  __shared__ float fin[BM];

  const int tid  = threadIdx.x;
  const int wid  = tid >> 6;
  const int lane = tid & 63;
  const int l31  = lane & 31;
  const int h    = lane >> 5;
  const int brow = blockIdx.x * BM;

  // per-lane byte base into a B sub-image (wave's 2 cb-blocks at wid*2048)
  const char* bbase = (const char*)bpack + wid * 2048 + (l31 * 2 + h) * 16;

#define LOADB8(S, DST)                                                         \
  {                                                                            \
    const char* p_ = bbase + (size_t)((S) & 31) * 32768;                       \
    (DST)[0] = *(const f16x8*)(p_);            /* jh0 ks0 cb-even */           \
    (DST)[1] = *(const f16x8*)(p_ + 1024);     /* jh0 ks0 cb-odd  */           \
    (DST)[2] = *(const f16x8*)(p_ + 16384);    /* jh0 ks1 cb-even */           \
    (DST)[3] = *(const f16x8*)(p_ + 17408);    /* jh0 ks1 cb-odd  */           \
    (DST)[4] = *(const f16x8*)(p_ + 32768);    /* jh1 ks0 cb-even */           \
    (DST)[5] = *(const f16x8*)(p_ + 33792);    /* jh1 ks0 cb-odd  */           \
    (DST)[6] = *(const f16x8*)(p_ + 49152);    /* jh1 ks1 cb-even */           \
    (DST)[7] = *(const f16x8*)(p_ + 50176);    /* jh1 ks1 cb-odd  */           \
  }
#define COMPUTE16(B)                                                           \
  {                                                                            \
    _Pragma("unroll")                                                          \
    for (int j2_ = 0; j2_ < 2; ++j2_)                                          \
      _Pragma("unroll")                                                        \
      for (int ks_ = 0; ks_ < 2; ++ks_)                                        \
        _Pragma("unroll")                                                      \
        for (int c2_ = 0; c2_ < 2; ++c2_)                                      \
          _Pragma("unroll")                                                    \
          for (int rb_ = 0; rb_ < 2; ++rb_)                                    \
            acc[rb_][j2_ * 2 + c2_] = __builtin_amdgcn_mfma_f32_32x32x16_f16(  \
                a[rb_][ks_], (B)[j2_ * 4 + ks_ * 2 + c2_],                     \
                acc[rb_][j2_ * 2 + c2_], 0, 0, 0);                             \
  }

  f16x8 bA[8], bB[8];

  // issue first slice's B loads before staging (covers L2 latency)
  LOADB8(0, bA)

  // ---- stage x panel -> LDS fp16 (coalesced reads, swizzled writes) ----
  {
    const float* xsrc = x + (size_t)brow * D_DIM;
    #pragma unroll
    for (int it = 0; it < 16; ++it) {
      const int idx = it * 512 + tid;            // float4 index
      const int r = idx >> 7, f = idx & 127;
      f32x4v v = __builtin_nontemporal_load(
          (const f32x4v*)(xsrc + (size_t)r * D_DIM + f * 4));
      f16x4 h4;
      h4[0] = (f16_t)v[0]; h4[1] = (f16_t)v[1];
      h4[2] = (f16_t)v[2]; h4[3] = (f16_t)v[3];
      *(f16x4*)(Ax + r * 1024 + ((f * 8) ^ ((r & 7) << 4))) = h4;
    }
  }
  __syncthreads();   // the ONLY pre-epilogue barrier

  f32x16 acc[2][4];
  #pragma unroll
  for (int rb = 0; rb < 2; ++rb)
    #pragma unroll
    for (int cc = 0; cc < 4; ++cc)
      #pragma unroll
      for (int e = 0; e < 16; ++e) acc[rb][cc][e] = 0.f;

  const char* abase0 = Ax + l31 * 1024;          // rb=0 rows; rb=1 at +32KB
  const int swz = (l31 & 7) << 4;
  const int h16 = h * 16;
  f16x8 a[2][2];

  // ---- main loop: 16 slices, barrier-free ----
  #pragma unroll
  for (int tt = 0; tt < 8; ++tt) {
    {  // slice T = 2*tt : compute bA, prefetch bB
      const int T = 2 * tt;
      LOADB8(2 * (T + 1), bB)
      const int o0 = (T * 64 + h16) ^ swz;
      const int o1 = o0 ^ 32;
      a[0][0] = *(const f16x8*)(abase0 + o0);
      a[0][1] = *(const f16x8*)(abase0 + o1);
      a[1][0] = *(const f16x8*)(abase0 + 32768 + o0);
      a[1][1] = *(const f16x8*)(abase0 + 32768 + o1);
      COMPUTE16(bA)
    }
    {  // slice T = 2*tt+1 : compute bB, prefetch bA
      const int T = 2 * tt + 1;
      if (T < 15) LOADB8(2 * (T + 1), bA)
      const int o0 = (T * 64 + h16) ^ swz;
      const int o1 = o0 ^ 32;
      a[0][0] = *(const f16x8*)(abase0 + o0);
      a[0][1] = *(const f16x8*)(abase0 + o1);
      a[1][0] = *(const f16x8*)(abase0 + 32768 + o0);
      a[1][1] = *(const f16x8*)(abase0 + 32768 + o1);
      COMPUTE16(bB)
    }
  }

  // ---- epilogue: fused softmax over 1024 columns ----
  // col(cc) = (cc>>1)*512 + wid*64 + (cc&1)*32 + l31
  // row(rb,reg) = rb*32 + (reg&3) + 8*(reg>>2) + 4*h
  float bcol[4];
  #pragma unroll
  for (int cc = 0; cc < 4; ++cc)
    bcol[cc] = bias[(cc >> 1) * 512 + wid * 64 + (cc & 1) * 32 + l31];

  float rr[2][16];
  #pragma unroll
  for (int rb = 0; rb < 2; ++rb)
    #pragma unroll
    for (int reg = 0; reg < 16; ++reg) {
      float m = -3.0e38f;
      #pragma unroll
      for (int cc = 0; cc < 4; ++cc) {
        float v = acc[rb][cc][reg] + bcol[cc];
        acc[rb][cc][reg] = v;
        m = fmaxf(m, v);
      }
      m = fmaxf(m, __shfl_xor(m, 1, 64));
      m = fmaxf(m, __shfl_xor(m, 2, 64));
      m = fmaxf(m, __shfl_xor(m, 4, 64));
      m = fmaxf(m, __shfl_xor(m, 8, 64));
      m = fmaxf(m, __shfl_xor(m, 16, 64));
      rr[rb][reg] = m;
    }
  __syncthreads();   // all waves past the K-loop before red reuse
  if (l31 == 0) {    // lanes 0 and 32 (h=0,1) cover distinct rows
    #pragma unroll
    for (int rb = 0; rb < 2; ++rb)
      #pragma unroll
      for (int reg = 0; reg < 16; ++reg)
        red[wid * BM + rb * 32 + (reg & 3) + 8 * (reg >> 2) + 4 * h] = rr[rb][reg];
  }
  __syncthreads();
  if (tid < BM) {
    float m = red[tid];
    #pragma unroll
    for (int w = 1; w < WAVES; ++w) m = fmaxf(m, red[w * BM + tid]);
    fin[tid] = m;
  }
  __syncthreads();

  #pragma unroll
  for (int rb = 0; rb < 2; ++rb)
    #pragma unroll
    for (int reg = 0; reg < 16; ++reg) {
      const float m = fin[rb * 32 + (reg & 3) + 8 * (reg >> 2) + 4 * h];
      float s = 0.f;
      #pragma unroll
      for (int cc = 0; cc < 4; ++cc) {
        float e = __expf(acc[rb][cc][reg] - m);
        acc[rb][cc][reg] = e;
        s += e;
      }
      s += __shfl_xor(s, 1, 64);
      s += __shfl_xor(s, 2, 64);
      s += __shfl_xor(s, 4, 64);
      s += __shfl_xor(s, 8, 64);
      s += __shfl_xor(s, 16, 64);
      rr[rb][reg] = s;
    }
  __syncthreads();   // fin(max) reads done before red overwrite
  if (l31 == 0) {
    #pragma unroll
    for (int rb = 0; rb < 2; ++rb)
      #pragma unroll
      for (int reg = 0; reg < 16; ++reg)
        red[wid * BM + rb * 32 + (reg & 3) + 8 * (reg >> 2) + 4 * h] = rr[rb][reg];
  }
  __syncthreads();
  if (tid < BM) {
    float s = 0.f;
    #pragma unroll
    for (int w = 0; w < WAVES; ++w) s += red[w * BM + tid];
    fin[tid] = 1.0f / s;
  }
  __syncthreads();

  #pragma unroll
  for (int rb = 0; rb < 2; ++rb)
    #pragma unroll
    for (int reg = 0; reg < 16; ++reg) {
      const int row = rb * 32 + (reg & 3) + 8 * (reg >> 2) + 4 * h;
      const float rs = fin[row];
      #pragma unroll
      for (int cc = 0; cc < 4; ++cc) {
        const int col = (cc >> 1) * 512 + wid * 64 + (cc & 1) * 32 + l31;
        __builtin_nontemporal_store(acc[rb][cc][reg] * rs,
                                    &out[(size_t)(brow + row) * K_CL + col]);
      }
    }
}

extern "C" void kernel_launch(void* const* d_in, const int* in_sizes, int n_in,
                              void* d_out, int out_size, void* d_ws, size_t ws_size,
                              hipStream_t stream) {
  const float* x       = (const float*)d_in[0];   // [32768, 512] fp32
  const float* centers = (const float*)d_in[1];   // [1024, 512] fp32
  float* out = (float*)d_out;                     // [32768, 1024] fp32

  f16_t* bpack = (f16_t*)d_ws;                                   // 32*32KB = 1MB
  float* bias  = (float*)((char*)d_ws + (size_t)32 * 32768);     // 4KB

  prep_kernel<<<K_CL, 64, 0, stream>>>(centers, bpack, bias);
  cluster_kernel<<<N_ROWS / BM, THREADS, 0, stream>>>(x, bpack, bias, out);
}